// Round 15
// baseline (419.280 us; speedup 1.0000x reference)
//
#include <hip/hip_runtime.h>
#include <hip/hip_bf16.h>
#include <math.h>

#define HID 64
#define IN_DIM 256
#define NPB 400          // nodes per bucket
#define NB  250          // buckets (N/NPB)
#define CAP 14336        // padded per-bucket segment (mean 12800, sd ~113)
#define TILE 8192        // edges per bucket_fill block
#define NW  32           // src windows per node key (src>>12 -> 0..24, padded to 32)
#define NKEY (NPB * NW)  // 12800 counting-sort keys per bucket (52.5 KB smem)

typedef unsigned short u16;
typedef unsigned int u32;

using bf16x8 = __attribute__((ext_vector_type(8))) short;
using f32x4  = __attribute__((ext_vector_type(4))) float;
using f16x2  = __attribute__((ext_vector_type(2))) _Float16;

__device__ __forceinline__ float bf2f(u16 v) {
    return __uint_as_float((u32)v << 16);
}
__device__ __forceinline__ u16 f2bf(float f) {
    __hip_bfloat16 b = __float2bfloat16(f);  // RNE
    return *(u16*)&b;
}
__device__ __forceinline__ u16 f2h(float f) {
    union { _Float16 h; u16 u; } c;
    c.h = (_Float16)f;
    return c.u;
}
__device__ __forceinline__ f16x2 u2h(u32 u) {
    union { u32 i; f16x2 h; } c;
    c.i = u;
    return c.h;
}

// ---------------- cursor init: bcur[b] = b*CAP ----------------
__global__ __launch_bounds__(256) void binit(int* __restrict__ bcur) {
    int b = threadIdx.x + blockIdx.x * 256;
    if (b < NB) bcur[b] = b * CAP;
}

// ---------------- pass 1: multisplit edges into padded dst-range buckets --------
// bpair[slot] = {src, dstLocal<<22 | eid}
__global__ __launch_bounds__(256) void bucket_fill(const int* __restrict__ src,
                                                   const int* __restrict__ dst,
                                                   int* __restrict__ bcur,
                                                   int2* __restrict__ bpair, int E) {
    __shared__ int hist[NB], cnt2[NB], gbase[NB];
    int tid = threadIdx.x;
    int base = blockIdx.x * TILE;
    for (int i = tid; i < NB; i += 256) { hist[i] = 0; cnt2[i] = 0; }
    __syncthreads();
    for (int i = 0; i < TILE / 256; ++i) {
        int e = base + i * 256 + tid;
        if (e < E) atomicAdd(&hist[dst[e] / NPB], 1);
    }
    __syncthreads();
    for (int b = tid; b < NB; b += 256)
        if (hist[b]) gbase[b] = atomicAdd(&bcur[b], hist[b]);
    __syncthreads();
    for (int i = 0; i < TILE / 256; ++i) {
        int e = base + i * 256 + tid;
        if (e < E) {
            int d = dst[e];
            int b = d / NPB;
            int lp = atomicAdd(&cnt2[b], 1);
            bpair[gbase[b] + lp] = make_int2(src[e], ((d - b * NPB) << 22) | e);
        }
    }
}

// ---------------- pass 2: counting sort by (dstLocal, srcWindow) ----------------
__global__ __launch_bounds__(512) void csr_scatter(const int* __restrict__ bcur,
                                                   const int2* __restrict__ bpair,
                                                   int* __restrict__ csr_src,
                                                   int* __restrict__ csr_eid,
                                                   int* __restrict__ noff,
                                                   int* __restrict__ ndeg,
                                                   float* __restrict__ dinv) {
    extern __shared__ int smem[];
    int* cnt  = smem;               // [NKEY]
    int* tsum = smem + NKEY;        // [512]
    int* wsum = smem + NKEY + 512;  // [8]
    int tid = threadIdx.x, b = blockIdx.x;
    int node0 = b * NPB;
    int pbeg = b * CAP;
    int cntE = bcur[b] - pbeg;

    for (int i = tid; i < NKEY; i += 512) cnt[i] = 0;
    __syncthreads();
    for (int i = tid; i < cntE; i += 512) {
        int2 p = bpair[pbeg + i];
        int key = (((p.y >> 22) & 511) << 5) | ((u32)p.x >> 12);
        atomicAdd(&cnt[key], 1);
    }
    __syncthreads();
    {
        int base = tid * (NKEY / 512);
        int s = 0;
#pragma unroll
        for (int j = 0; j < NKEY / 512; ++j) s += cnt[base + j];
        tsum[tid] = s;
    }
    __syncthreads();
    {
        int lane = tid & 63, wid = tid >> 6;
        int v = tsum[tid];
        int incl = v;
#pragma unroll
        for (int s = 1; s < 64; s <<= 1) {
            int t = __shfl_up(incl, s, 64);
            if (lane >= s) incl += t;
        }
        if (lane == 63) wsum[wid] = incl;
        __syncthreads();
        if (tid == 0) {
            int run = 0;
#pragma unroll
            for (int w = 0; w < 8; ++w) { int t = wsum[w]; wsum[w] = run; run += t; }
        }
        __syncthreads();
        tsum[tid] = wsum[wid] + incl - v;   // exclusive prefix
    }
    __syncthreads();
    {
        int base = tid * (NKEY / 512);
        int run = tsum[tid];
#pragma unroll
        for (int j = 0; j < NKEY / 512; ++j) {
            int cv = cnt[base + j];
            cnt[base + j] = run;
            run += cv;
        }
    }
    __syncthreads();
    for (int dl = tid; dl < NPB; dl += 512) {
        int beg = cnt[dl << 5];
        int end = (dl < NPB - 1) ? cnt[(dl + 1) << 5] : cntE;
        noff[node0 + dl] = pbeg + beg;
        ndeg[node0 + dl] = end - beg;
        dinv[node0 + dl] = rsqrtf((float)(end - beg) + 1.0f);
    }
    __syncthreads();
    for (int i = tid; i < cntE; i += 512) {
        int2 p = bpair[pbeg + i];
        int key = (((p.y >> 22) & 511) << 5) | ((u32)p.x >> 12);
        int pos = atomicAdd(&cnt[key], 1);
        csr_src[pbeg + pos] = p.x;
        csr_eid[pbeg + pos] = p.y & 0x3FFFFF;
    }
}

// ---------------- MFMA GEMM: out = A[N,K] @ W[K,COLS] (hi/lo split) ----------------
// MODE 0: out_b = bf16(acc*dinv)            (COLS=64, for gathers)
// MODE 2: out_b = fp16(acc) cols 0-63 (a);  out_c = fp16(acc+bias) cols 64-127 (c)
template<int K, int COLS, int MODE>
__global__ __launch_bounds__(256) void mfma_gemm(const float* __restrict__ A,
                                                 const float* __restrict__ W,
                                                 const float* __restrict__ dinv,
                                                 const float* __restrict__ bias,
                                                 u16* __restrict__ out_b,
                                                 u16* __restrict__ out_c,
                                                 int N) {
    constexpr int KP = K + 8;
    constexpr int NT = COLS / 16;
    __shared__ __align__(16) u16 Wh[COLS * KP];
    __shared__ __align__(16) u16 Wl[COLS * KP];

    const int tid  = threadIdx.x;
    const int wave = tid >> 6;
    const int lane = tid & 63;
    const int lr   = lane & 15;
    const int kg   = lane >> 4;
    const int row0 = blockIdx.x * 64;

    for (int e = tid; e < K * COLS; e += 256) {
        int k = e / COLS, c = e % COLS;
        int gidx = (MODE == 2) ? (((c >> 6) * K + k) * 64 + (c & 63)) : e;
        float f = W[gidx];
        u16 hi = f2bf(f);
        u16 lo = f2bf(f - bf2f(hi));
        Wh[c * KP + k] = hi;
        Wl[c * KP + k] = lo;
    }
    __syncthreads();

    const int arow = row0 + wave * 16 + lr;
    const float* ar = A + (size_t)(arow < N ? arow : N - 1) * K + kg * 8;

    f32x4 acc[NT];
#pragma unroll
    for (int c = 0; c < NT; ++c) acc[c] = (f32x4){0.f, 0.f, 0.f, 0.f};

#pragma unroll
    for (int ks = 0; ks < K; ks += 32) {
        float4 v0 = *(const float4*)(ar + ks);
        float4 v1 = *(const float4*)(ar + ks + 4);
        bf16x8 ah, al;
        {
            u16 h0 = f2bf(v0.x), h1 = f2bf(v0.y), h2 = f2bf(v0.z), h3 = f2bf(v0.w);
            u16 h4 = f2bf(v1.x), h5 = f2bf(v1.y), h6 = f2bf(v1.z), h7 = f2bf(v1.w);
            ah = (bf16x8){(short)h0, (short)h1, (short)h2, (short)h3,
                          (short)h4, (short)h5, (short)h6, (short)h7};
            al = (bf16x8){(short)f2bf(v0.x - bf2f(h0)), (short)f2bf(v0.y - bf2f(h1)),
                          (short)f2bf(v0.z - bf2f(h2)), (short)f2bf(v0.w - bf2f(h3)),
                          (short)f2bf(v1.x - bf2f(h4)), (short)f2bf(v1.y - bf2f(h5)),
                          (short)f2bf(v1.z - bf2f(h6)), (short)f2bf(v1.w - bf2f(h7))};
        }
#pragma unroll
        for (int c = 0; c < NT; ++c) {
            const int wrow = c * 16 + lr;
            bf16x8 bh = *(const bf16x8*)(Wh + wrow * KP + ks + kg * 8);
            bf16x8 bl = *(const bf16x8*)(Wl + wrow * KP + ks + kg * 8);
            acc[c] = __builtin_amdgcn_mfma_f32_16x16x32_bf16(ah, bh, acc[c], 0, 0, 0);
            acc[c] = __builtin_amdgcn_mfma_f32_16x16x32_bf16(ah, bl, acc[c], 0, 0, 0);
            acc[c] = __builtin_amdgcn_mfma_f32_16x16x32_bf16(al, bh, acc[c], 0, 0, 0);
        }
    }

#pragma unroll
    for (int rr = 0; rr < 4; ++rr) {
        int n = row0 + wave * 16 + kg * 4 + rr;
        if (n >= N) continue;
        float dv = (MODE == 0) ? dinv[n] : 1.f;
#pragma unroll
        for (int c = 0; c < NT; ++c) {
            int col = c * 16 + lr;
            float v = acc[c][rr];
            if (MODE == 0) {
                out_b[(size_t)n * 64 + col] = f2bf(v * dv);
            } else {
                if (col < 64) out_b[(size_t)n * 64 + col] = f2h(v);
                else out_c[(size_t)n * 64 + (col - 64)] = f2h(v + bias[col - 64]);
            }
        }
    }
}

// ---------------- gather: 8 features/lane, 8-deep pipelined edge loop ----------------
__global__ __launch_bounds__(256) void gather_kernel(const int* __restrict__ noff,
                                                     const int* __restrict__ ndeg,
                                                     const int* __restrict__ csr_src,
                                                     const u16* __restrict__ ts,
                                                     const float* __restrict__ dinv,
                                                     const float* __restrict__ bias,
                                                     float* __restrict__ outh, int N,
                                                     int do_relu) {
    long tid = (long)blockIdx.x * blockDim.x + threadIdx.x;
    int v = (int)(tid >> 6), j = (int)(tid & 63);
    if (v >= N) return;
    int l = j & 7, g = j >> 3;
    const uint4* tp = (const uint4*)ts;
    float a0 = 0.f, a1 = 0.f, a2 = 0.f, a3 = 0.f;
    float a4 = 0.f, a5 = 0.f, a6 = 0.f, a7 = 0.f;
    int beg = noff[v], end = beg + ndeg[v];

#define ACCUM(U)                              \
    a0 += __uint_as_float((U).x << 16);       \
    a1 += __uint_as_float((U).x & 0xffff0000u); \
    a2 += __uint_as_float((U).y << 16);       \
    a3 += __uint_as_float((U).y & 0xffff0000u); \
    a4 += __uint_as_float((U).z << 16);       \
    a5 += __uint_as_float((U).z & 0xffff0000u); \
    a6 += __uint_as_float((U).w << 16);       \
    a7 += __uint_as_float((U).w & 0xffff0000u);

    int k = beg + g;
    while (k + 56 < end) {   // 8 edges for this group in flight
        int s0 = csr_src[k];
        int s1 = csr_src[k + 8];
        int s2 = csr_src[k + 16];
        int s3 = csr_src[k + 24];
        int s4 = csr_src[k + 32];
        int s5 = csr_src[k + 40];
        int s6 = csr_src[k + 48];
        int s7 = csr_src[k + 56];
        uint4 u0 = tp[((u32)s0 << 3) + l];
        uint4 u1 = tp[((u32)s1 << 3) + l];
        uint4 u2 = tp[((u32)s2 << 3) + l];
        uint4 u3 = tp[((u32)s3 << 3) + l];
        uint4 u4 = tp[((u32)s4 << 3) + l];
        uint4 u5 = tp[((u32)s5 << 3) + l];
        uint4 u6 = tp[((u32)s6 << 3) + l];
        uint4 u7 = tp[((u32)s7 << 3) + l];
        ACCUM(u0); ACCUM(u1); ACCUM(u2); ACCUM(u3);
        ACCUM(u4); ACCUM(u5); ACCUM(u6); ACCUM(u7);
        k += 64;
    }
    while (k < end) {
        int s = csr_src[k];
        uint4 u = tp[((u32)s << 3) + l];
        ACCUM(u);
        k += 8;
    }
#pragma unroll
    for (int o = 8; o < 64; o <<= 1) {
        a0 += __shfl_xor(a0, o, 64);
        a1 += __shfl_xor(a1, o, 64);
        a2 += __shfl_xor(a2, o, 64);
        a3 += __shfl_xor(a3, o, 64);
        a4 += __shfl_xor(a4, o, 64);
        a5 += __shfl_xor(a5, o, 64);
        a6 += __shfl_xor(a6, o, 64);
        a7 += __shfl_xor(a7, o, 64);
    }
    uint4 su = tp[((u32)v << 3) + l];
    ACCUM(su);
#undef ACCUM
    float dv = dinv[v];
    const float* bp = bias + 8 * l;
    float4 b4a = *(const float4*)(bp);
    float4 b4b = *(const float4*)(bp + 4);
    float4 r0, r1;
    r0.x = a0 * dv + b4a.x; r0.y = a1 * dv + b4a.y;
    r0.z = a2 * dv + b4a.z; r0.w = a3 * dv + b4a.w;
    r1.x = a4 * dv + b4b.x; r1.y = a5 * dv + b4b.y;
    r1.z = a6 * dv + b4b.z; r1.w = a7 * dv + b4b.w;
    if (do_relu) {
        r0.x = fmaxf(r0.x, 0.f); r0.y = fmaxf(r0.y, 0.f);
        r0.z = fmaxf(r0.z, 0.f); r0.w = fmaxf(r0.w, 0.f);
        r1.x = fmaxf(r1.x, 0.f); r1.y = fmaxf(r1.y, 0.f);
        r1.z = fmaxf(r1.z, 0.f); r1.w = fmaxf(r1.w, 0.f);
    }
    if (g == 0) {
        float* op = outh + ((u32)v << 6) + 8 * l;
        *(float4*)(op) = r0;
        *(float4*)(op + 4) = r1;
    }
}

// ---------------- node-centric decode: fp16 packed math, 4-deep pipelined --------
__global__ __launch_bounds__(256) void decode_kernel(const int* __restrict__ noff,
                                                     const int* __restrict__ ndeg,
                                                     const int* __restrict__ csr_src,
                                                     const int* __restrict__ csr_eid,
                                                     const u16* __restrict__ aH,
                                                     const u16* __restrict__ cH,
                                                     const float* __restrict__ Wl2,
                                                     const float* __restrict__ bl2,
                                                     float* __restrict__ out, int N) {
    long tid = (long)blockIdx.x * blockDim.x + threadIdx.x;
    int v = (int)(tid >> 6), j = (int)(tid & 63);
    if (v >= N) return;
    int l = j & 7, g = j >> 3;
    uint4 cu = *(const uint4*)(cH + ((u32)v << 6) + 8 * l);
    f16x2 c0 = u2h(cu.x), c1 = u2h(cu.y), c2 = u2h(cu.z), c3 = u2h(cu.w);
    const float* wv = Wl2 + 8 * l;
    f16x2 w0 = {(_Float16)wv[0], (_Float16)wv[1]};
    f16x2 w1 = {(_Float16)wv[2], (_Float16)wv[3]};
    f16x2 w2 = {(_Float16)wv[4], (_Float16)wv[5]};
    f16x2 w3 = {(_Float16)wv[6], (_Float16)wv[7]};
    const f16x2 zz = {(_Float16)0.f, (_Float16)0.f};
    float bl2v = bl2[0];
    const uint4* ap = (const uint4*)aH;
    int beg = noff[v], end = beg + ndeg[v];

#define EDGEP(U, P)                                                    \
    {                                                                  \
        f16x2 t;                                                       \
        t = u2h((U).x) + c0;                                           \
        t = __builtin_elementwise_max(t, zz);                          \
        P = __builtin_amdgcn_fdot2(t, w0, P, false);                   \
        t = u2h((U).y) + c1;                                           \
        t = __builtin_elementwise_max(t, zz);                          \
        P = __builtin_amdgcn_fdot2(t, w1, P, false);                   \
        t = u2h((U).z) + c2;                                           \
        t = __builtin_elementwise_max(t, zz);                          \
        P = __builtin_amdgcn_fdot2(t, w2, P, false);                   \
        t = u2h((U).w) + c3;                                           \
        t = __builtin_elementwise_max(t, zz);                          \
        P = __builtin_amdgcn_fdot2(t, w3, P, false);                   \
    }

    int k = beg + g;
    while (k + 24 < end) {   // 4 edges for this group in flight
        int s0 = csr_src[k];
        int s1 = csr_src[k + 8];
        int s2 = csr_src[k + 16];
        int s3 = csr_src[k + 24];
        int e0 = csr_eid[k];
        int e1 = csr_eid[k + 8];
        int e2 = csr_eid[k + 16];
        int e3 = csr_eid[k + 24];
        uint4 u0 = ap[((u32)s0 << 3) + l];
        uint4 u1 = ap[((u32)s1 << 3) + l];
        uint4 u2 = ap[((u32)s2 << 3) + l];
        uint4 u3 = ap[((u32)s3 << 3) + l];
        float p0 = 0.f, p1 = 0.f, p2 = 0.f, p3 = 0.f;
        EDGEP(u0, p0);
        EDGEP(u1, p1);
        EDGEP(u2, p2);
        EDGEP(u3, p3);
        p0 += __shfl_xor(p0, 1, 64);
        p1 += __shfl_xor(p1, 1, 64);
        p2 += __shfl_xor(p2, 1, 64);
        p3 += __shfl_xor(p3, 1, 64);
        p0 += __shfl_xor(p0, 2, 64);
        p1 += __shfl_xor(p1, 2, 64);
        p2 += __shfl_xor(p2, 2, 64);
        p3 += __shfl_xor(p3, 2, 64);
        p0 += __shfl_xor(p0, 4, 64);
        p1 += __shfl_xor(p1, 4, 64);
        p2 += __shfl_xor(p2, 4, 64);
        p3 += __shfl_xor(p3, 4, 64);
        if (l == 0) {
            out[e0] = __builtin_amdgcn_rcpf(1.f + __expf(-(p0 + bl2v)));
            out[e1] = __builtin_amdgcn_rcpf(1.f + __expf(-(p1 + bl2v)));
            out[e2] = __builtin_amdgcn_rcpf(1.f + __expf(-(p2 + bl2v)));
            out[e3] = __builtin_amdgcn_rcpf(1.f + __expf(-(p3 + bl2v)));
        }
        k += 32;
    }
    while (k < end) {
        int s0 = csr_src[k];
        int e0 = csr_eid[k];
        uint4 u0 = ap[((u32)s0 << 3) + l];
        float p0 = 0.f;
        EDGEP(u0, p0);
        p0 += __shfl_xor(p0, 1, 64);
        p0 += __shfl_xor(p0, 2, 64);
        p0 += __shfl_xor(p0, 4, 64);
        if (l == 0) out[e0] = __builtin_amdgcn_rcpf(1.f + __expf(-(p0 + bl2v)));
        k += 8;
    }
#undef EDGEP
}

extern "C" void kernel_launch(void* const* d_in, const int* in_sizes, int n_in,
                              void* d_out, int out_size, void* d_ws, size_t ws_size,
                              hipStream_t stream) {
    const float* x   = (const float*)d_in[0];
    const int*   ei  = (const int*)d_in[1];
    const float* W1  = (const float*)d_in[2];
    const float* b1  = (const float*)d_in[3];
    const float* W2  = (const float*)d_in[4];
    const float* b2  = (const float*)d_in[5];
    const float* Wl1 = (const float*)d_in[6];
    const float* bl1 = (const float*)d_in[7];
    const float* Wl2 = (const float*)d_in[8];
    const float* bl2 = (const float*)d_in[9];
    float* out = (float*)d_out;

    const int N = in_sizes[0] / IN_DIM;   // 100000
    const int E = in_sizes[1] / 2;        // 3200000
    const int* src = ei;
    const int* dst = ei + E;

    // workspace layout
    char* ws = (char*)d_ws;
    float* dinv    = (float*)ws;  ws += (size_t)(N + 64) * 4;
    int*   noff    = (int*)ws;    ws += (size_t)(N + 64) * 4;
    int*   ndeg    = (int*)ws;    ws += (size_t)(N + 64) * 4;
    int*   bcur    = (int*)ws;    ws += 1024;
    int*   csr_src = (int*)ws;    ws += (size_t)NB * CAP * 4;   // 14.3 MB
    int*   csr_eid = (int*)ws;    ws += (size_t)NB * CAP * 4;   // 14.3 MB
    u16*   tb      = (u16*)ws;    ws += (size_t)N * HID * 2;    // t1, t2 (bf16), a (fp16)
    float* h       = (float*)ws;  ws += (size_t)N * HID * 4;    // h, then z
    float* c       = (float*)ws;  ws += (size_t)N * HID * 4;
    u16*   cH      = (u16*)c;     // fp16 c(+bias) for decode (reuses c region)
    int2*  bpair   = (int2*)h;    // overlay: CSR-build staging (dead before gather1)

    const int TPB = 256;
    long nodeT = (long)N * HID;
    int nodeBlocks = (int)((nodeT + TPB - 1) / TPB);
    int tBlocks = (E + TILE - 1) / TILE;
    int gBlocks = (N + 63) / 64;
    size_t sortBytes = (size_t)(NKEY + 512 + 8) * sizeof(int);   // ~52.5 KB -> 2 blocks/CU

    // ---- CSR build: padded fill -> (dl, window) counting sort ----
    binit<<<1, TPB, 0, stream>>>(bcur);
    bucket_fill<<<tBlocks, TPB, 0, stream>>>(src, dst, bcur, bpair, E);
    csr_scatter<<<NB, 512, sortBytes, stream>>>(bcur, bpair, csr_src, csr_eid,
                                                noff, ndeg, dinv);

    // ---- conv1: t1 = bf16((x@W1)*dinv) ; h = relu(gather + b1) ----
    mfma_gemm<IN_DIM, 64, 0><<<gBlocks, TPB, 0, stream>>>(x, W1, dinv, nullptr, tb, nullptr, N);
    gather_kernel<<<nodeBlocks, TPB, 0, stream>>>(noff, ndeg, csr_src, tb, dinv, b1, h, N, 1);

    // ---- conv2: t2 = bf16((h@W2)*dinv) ; z = gather + b2 (into h) ----
    mfma_gemm<HID, 64, 0><<<gBlocks, TPB, 0, stream>>>(h, W2, dinv, nullptr, tb, nullptr, N);
    gather_kernel<<<nodeBlocks, TPB, 0, stream>>>(noff, ndeg, csr_src, tb, dinv, b2, h, N, 0);

    // ---- decoder precompute: a = fp16(z@Wl1_top) into tb, cH = fp16(z@Wl1_bot + bl1) ----
    mfma_gemm<HID, 128, 2><<<gBlocks, TPB, 0, stream>>>(h, Wl1, nullptr, bl1, tb, cH, N);

    // ---- node-centric decode (fp16 packed, 4-deep) ----
    decode_kernel<<<nodeBlocks, TPB, 0, stream>>>(noff, ndeg, csr_src, csr_eid, tb, cH,
                                                  Wl2, bl2, out, N);
}

// Round 16
// 405.446 us; speedup vs baseline: 1.0341x; 1.0341x over previous
//
#include <hip/hip_runtime.h>
#include <hip/hip_bf16.h>
#include <math.h>

#define HID 64
#define IN_DIM 256
#define NPB 400          // nodes per bucket
#define NB  250          // buckets (N/NPB)
#define CAP 14336        // padded per-bucket segment (mean 12800, sd ~113)
#define TILE 8192        // edges per bucket_fill block
#define NW  64           // src windows per node key (src>>11 -> 0..48, padded to 64)
#define NKEY (NPB * NW)  // 25600 counting-sort keys per bucket

typedef unsigned short u16;
typedef unsigned int u32;

using bf16x8 = __attribute__((ext_vector_type(8))) short;
using f32x4  = __attribute__((ext_vector_type(4))) float;
using f16x2  = __attribute__((ext_vector_type(2))) _Float16;

__device__ __forceinline__ float bf2f(u16 v) {
    return __uint_as_float((u32)v << 16);
}
__device__ __forceinline__ u16 f2bf(float f) {
    __hip_bfloat16 b = __float2bfloat16(f);  // RNE
    return *(u16*)&b;
}
__device__ __forceinline__ u16 f2h(float f) {
    union { _Float16 h; u16 u; } c;
    c.h = (_Float16)f;
    return c.u;
}
__device__ __forceinline__ f16x2 u2h(u32 u) {
    union { u32 i; f16x2 h; } c;
    c.i = u;
    return c.h;
}

// ---------------- cursor init: bcur[b] = b*CAP ----------------
__global__ __launch_bounds__(256) void binit(int* __restrict__ bcur) {
    int b = threadIdx.x + blockIdx.x * 256;
    if (b < NB) bcur[b] = b * CAP;
}

// ---------------- pass 1: multisplit edges into padded dst-range buckets --------
// bpair[slot] = {src, dstLocal<<22 | eid}
__global__ __launch_bounds__(256) void bucket_fill(const int* __restrict__ src,
                                                   const int* __restrict__ dst,
                                                   int* __restrict__ bcur,
                                                   int2* __restrict__ bpair, int E) {
    __shared__ int hist[NB], cnt2[NB], gbase[NB];
    int tid = threadIdx.x;
    int base = blockIdx.x * TILE;
    for (int i = tid; i < NB; i += 256) { hist[i] = 0; cnt2[i] = 0; }
    __syncthreads();
    for (int i = 0; i < TILE / 256; ++i) {
        int e = base + i * 256 + tid;
        if (e < E) atomicAdd(&hist[dst[e] / NPB], 1);
    }
    __syncthreads();
    for (int b = tid; b < NB; b += 256)
        if (hist[b]) gbase[b] = atomicAdd(&bcur[b], hist[b]);
    __syncthreads();
    for (int i = 0; i < TILE / 256; ++i) {
        int e = base + i * 256 + tid;
        if (e < E) {
            int d = dst[e];
            int b = d / NPB;
            int lp = atomicAdd(&cnt2[b], 1);
            bpair[gbase[b] + lp] = make_int2(src[e], ((d - b * NPB) << 22) | e);
        }
    }
}

// ---------------- pass 2: counting sort by (dstLocal, srcWindow) ----------------
__global__ __launch_bounds__(512) void csr_scatter(const int* __restrict__ bcur,
                                                   const int2* __restrict__ bpair,
                                                   int* __restrict__ csr_src,
                                                   int* __restrict__ csr_eid,
                                                   int* __restrict__ noff,
                                                   int* __restrict__ ndeg,
                                                   float* __restrict__ dinv) {
    extern __shared__ int smem[];
    int* cnt  = smem;               // [NKEY]
    int* tsum = smem + NKEY;        // [512]
    int* wsum = smem + NKEY + 512;  // [8]
    int tid = threadIdx.x, b = blockIdx.x;
    int node0 = b * NPB;
    int pbeg = b * CAP;
    int cntE = bcur[b] - pbeg;

    for (int i = tid; i < NKEY; i += 512) cnt[i] = 0;
    __syncthreads();
    for (int i = tid; i < cntE; i += 512) {
        int2 p = bpair[pbeg + i];
        int key = (((p.y >> 22) & 511) << 6) | ((u32)p.x >> 11);
        atomicAdd(&cnt[key], 1);
    }
    __syncthreads();
    {
        int base = tid * (NKEY / 512);
        int s = 0;
#pragma unroll
        for (int j = 0; j < NKEY / 512; ++j) s += cnt[base + j];
        tsum[tid] = s;
    }
    __syncthreads();
    {
        int lane = tid & 63, wid = tid >> 6;
        int v = tsum[tid];
        int incl = v;
#pragma unroll
        for (int s = 1; s < 64; s <<= 1) {
            int t = __shfl_up(incl, s, 64);
            if (lane >= s) incl += t;
        }
        if (lane == 63) wsum[wid] = incl;
        __syncthreads();
        if (tid == 0) {
            int run = 0;
#pragma unroll
            for (int w = 0; w < 8; ++w) { int t = wsum[w]; wsum[w] = run; run += t; }
        }
        __syncthreads();
        tsum[tid] = wsum[wid] + incl - v;   // exclusive prefix
    }
    __syncthreads();
    {
        int base = tid * (NKEY / 512);
        int run = tsum[tid];
#pragma unroll
        for (int j = 0; j < NKEY / 512; ++j) {
            int cv = cnt[base + j];
            cnt[base + j] = run;
            run += cv;
        }
    }
    __syncthreads();
    for (int dl = tid; dl < NPB; dl += 512) {
        int beg = cnt[dl << 6];
        int end = (dl < NPB - 1) ? cnt[(dl + 1) << 6] : cntE;
        noff[node0 + dl] = pbeg + beg;
        ndeg[node0 + dl] = end - beg;
        dinv[node0 + dl] = rsqrtf((float)(end - beg) + 1.0f);
    }
    __syncthreads();
    for (int i = tid; i < cntE; i += 512) {
        int2 p = bpair[pbeg + i];
        int key = (((p.y >> 22) & 511) << 6) | ((u32)p.x >> 11);
        int pos = atomicAdd(&cnt[key], 1);
        csr_src[pbeg + pos] = p.x;
        csr_eid[pbeg + pos] = p.y & 0x3FFFFF;
    }
}

// ---------------- MFMA GEMM: out = A[N,K] @ W[K,COLS] (hi/lo split) ----------------
// MODE 0: out_b = bf16(acc*dinv)            (COLS=64, for gathers)
// MODE 2: out_b = fp16(acc) cols 0-63 (a);  out_c = fp16(acc+bias) cols 64-127 (c)
template<int K, int COLS, int MODE>
__global__ __launch_bounds__(256) void mfma_gemm(const float* __restrict__ A,
                                                 const float* __restrict__ W,
                                                 const float* __restrict__ dinv,
                                                 const float* __restrict__ bias,
                                                 u16* __restrict__ out_b,
                                                 u16* __restrict__ out_c,
                                                 int N) {
    constexpr int KP = K + 8;
    constexpr int NT = COLS / 16;
    __shared__ __align__(16) u16 Wh[COLS * KP];
    __shared__ __align__(16) u16 Wl[COLS * KP];

    const int tid  = threadIdx.x;
    const int wave = tid >> 6;
    const int lane = tid & 63;
    const int lr   = lane & 15;
    const int kg   = lane >> 4;
    const int row0 = blockIdx.x * 64;

    for (int e = tid; e < K * COLS; e += 256) {
        int k = e / COLS, c = e % COLS;
        int gidx = (MODE == 2) ? (((c >> 6) * K + k) * 64 + (c & 63)) : e;
        float f = W[gidx];
        u16 hi = f2bf(f);
        u16 lo = f2bf(f - bf2f(hi));
        Wh[c * KP + k] = hi;
        Wl[c * KP + k] = lo;
    }
    __syncthreads();

    const int arow = row0 + wave * 16 + lr;
    const float* ar = A + (size_t)(arow < N ? arow : N - 1) * K + kg * 8;

    f32x4 acc[NT];
#pragma unroll
    for (int c = 0; c < NT; ++c) acc[c] = (f32x4){0.f, 0.f, 0.f, 0.f};

#pragma unroll
    for (int ks = 0; ks < K; ks += 32) {
        float4 v0 = *(const float4*)(ar + ks);
        float4 v1 = *(const float4*)(ar + ks + 4);
        bf16x8 ah, al;
        {
            u16 h0 = f2bf(v0.x), h1 = f2bf(v0.y), h2 = f2bf(v0.z), h3 = f2bf(v0.w);
            u16 h4 = f2bf(v1.x), h5 = f2bf(v1.y), h6 = f2bf(v1.z), h7 = f2bf(v1.w);
            ah = (bf16x8){(short)h0, (short)h1, (short)h2, (short)h3,
                          (short)h4, (short)h5, (short)h6, (short)h7};
            al = (bf16x8){(short)f2bf(v0.x - bf2f(h0)), (short)f2bf(v0.y - bf2f(h1)),
                          (short)f2bf(v0.z - bf2f(h2)), (short)f2bf(v0.w - bf2f(h3)),
                          (short)f2bf(v1.x - bf2f(h4)), (short)f2bf(v1.y - bf2f(h5)),
                          (short)f2bf(v1.z - bf2f(h6)), (short)f2bf(v1.w - bf2f(h7))};
        }
#pragma unroll
        for (int c = 0; c < NT; ++c) {
            const int wrow = c * 16 + lr;
            bf16x8 bh = *(const bf16x8*)(Wh + wrow * KP + ks + kg * 8);
            bf16x8 bl = *(const bf16x8*)(Wl + wrow * KP + ks + kg * 8);
            acc[c] = __builtin_amdgcn_mfma_f32_16x16x32_bf16(ah, bh, acc[c], 0, 0, 0);
            acc[c] = __builtin_amdgcn_mfma_f32_16x16x32_bf16(ah, bl, acc[c], 0, 0, 0);
            acc[c] = __builtin_amdgcn_mfma_f32_16x16x32_bf16(al, bh, acc[c], 0, 0, 0);
        }
    }

#pragma unroll
    for (int rr = 0; rr < 4; ++rr) {
        int n = row0 + wave * 16 + kg * 4 + rr;
        if (n >= N) continue;
        float dv = (MODE == 0) ? dinv[n] : 1.f;
#pragma unroll
        for (int c = 0; c < NT; ++c) {
            int col = c * 16 + lr;
            float v = acc[c][rr];
            if (MODE == 0) {
                out_b[(size_t)n * 64 + col] = f2bf(v * dv);
            } else {
                if (col < 64) out_b[(size_t)n * 64 + col] = f2h(v);
                else out_c[(size_t)n * 64 + (col - 64)] = f2h(v + bias[col - 64]);
            }
        }
    }
}

// ---------------- gather: 8 features/lane, 4-deep pipelined edge loop ----------------
__global__ __launch_bounds__(256) void gather_kernel(const int* __restrict__ noff,
                                                     const int* __restrict__ ndeg,
                                                     const int* __restrict__ csr_src,
                                                     const u16* __restrict__ ts,
                                                     const float* __restrict__ dinv,
                                                     const float* __restrict__ bias,
                                                     float* __restrict__ outh, int N,
                                                     int do_relu) {
    long tid = (long)blockIdx.x * blockDim.x + threadIdx.x;
    int v = (int)(tid >> 6), j = (int)(tid & 63);
    if (v >= N) return;
    int l = j & 7, g = j >> 3;
    const uint4* tp = (const uint4*)ts;
    float a0 = 0.f, a1 = 0.f, a2 = 0.f, a3 = 0.f;
    float a4 = 0.f, a5 = 0.f, a6 = 0.f, a7 = 0.f;
    int beg = noff[v], end = beg + ndeg[v];

#define ACCUM(U)                              \
    a0 += __uint_as_float((U).x << 16);       \
    a1 += __uint_as_float((U).x & 0xffff0000u); \
    a2 += __uint_as_float((U).y << 16);       \
    a3 += __uint_as_float((U).y & 0xffff0000u); \
    a4 += __uint_as_float((U).z << 16);       \
    a5 += __uint_as_float((U).z & 0xffff0000u); \
    a6 += __uint_as_float((U).w << 16);       \
    a7 += __uint_as_float((U).w & 0xffff0000u);

    int k = beg + g;
    while (k + 24 < end) {
        int s0 = csr_src[k];
        int s1 = csr_src[k + 8];
        int s2 = csr_src[k + 16];
        int s3 = csr_src[k + 24];
        uint4 u0 = tp[((u32)s0 << 3) + l];
        uint4 u1 = tp[((u32)s1 << 3) + l];
        uint4 u2 = tp[((u32)s2 << 3) + l];
        uint4 u3 = tp[((u32)s3 << 3) + l];
        ACCUM(u0); ACCUM(u1); ACCUM(u2); ACCUM(u3);
        k += 32;
    }
    while (k < end) {
        int s = csr_src[k];
        uint4 u = tp[((u32)s << 3) + l];
        ACCUM(u);
        k += 8;
    }
#pragma unroll
    for (int o = 8; o < 64; o <<= 1) {
        a0 += __shfl_xor(a0, o, 64);
        a1 += __shfl_xor(a1, o, 64);
        a2 += __shfl_xor(a2, o, 64);
        a3 += __shfl_xor(a3, o, 64);
        a4 += __shfl_xor(a4, o, 64);
        a5 += __shfl_xor(a5, o, 64);
        a6 += __shfl_xor(a6, o, 64);
        a7 += __shfl_xor(a7, o, 64);
    }
    uint4 su = tp[((u32)v << 3) + l];
    ACCUM(su);
#undef ACCUM
    float dv = dinv[v];
    const float* bp = bias + 8 * l;
    float4 b4a = *(const float4*)(bp);
    float4 b4b = *(const float4*)(bp + 4);
    float4 r0, r1;
    r0.x = a0 * dv + b4a.x; r0.y = a1 * dv + b4a.y;
    r0.z = a2 * dv + b4a.z; r0.w = a3 * dv + b4a.w;
    r1.x = a4 * dv + b4b.x; r1.y = a5 * dv + b4b.y;
    r1.z = a6 * dv + b4b.z; r1.w = a7 * dv + b4b.w;
    if (do_relu) {
        r0.x = fmaxf(r0.x, 0.f); r0.y = fmaxf(r0.y, 0.f);
        r0.z = fmaxf(r0.z, 0.f); r0.w = fmaxf(r0.w, 0.f);
        r1.x = fmaxf(r1.x, 0.f); r1.y = fmaxf(r1.y, 0.f);
        r1.z = fmaxf(r1.z, 0.f); r1.w = fmaxf(r1.w, 0.f);
    }
    if (g == 0) {
        float* op = outh + ((u32)v << 6) + 8 * l;
        *(float4*)(op) = r0;
        *(float4*)(op + 4) = r1;
    }
}

// ---------------- node-centric decode: fp16 packed math, 2-deep pipelined --------
// out[e] = sigmoid( sum_f relu(a[s]+c[d]) * w )  via v_pk_add/ v_pk_max / v_dot2
__global__ __launch_bounds__(256) void decode_kernel(const int* __restrict__ noff,
                                                     const int* __restrict__ ndeg,
                                                     const int* __restrict__ csr_src,
                                                     const int* __restrict__ csr_eid,
                                                     const u16* __restrict__ aH,
                                                     const u16* __restrict__ cH,
                                                     const float* __restrict__ Wl2,
                                                     const float* __restrict__ bl2,
                                                     float* __restrict__ out, int N) {
    long tid = (long)blockIdx.x * blockDim.x + threadIdx.x;
    int v = (int)(tid >> 6), j = (int)(tid & 63);
    if (v >= N) return;
    int l = j & 7, g = j >> 3;
    // per-lane constants: 8 features (4 fp16 pairs) of c[v] and Wl2
    uint4 cu = *(const uint4*)(cH + ((u32)v << 6) + 8 * l);
    f16x2 c0 = u2h(cu.x), c1 = u2h(cu.y), c2 = u2h(cu.z), c3 = u2h(cu.w);
    const float* wv = Wl2 + 8 * l;
    f16x2 w0 = {(_Float16)wv[0], (_Float16)wv[1]};
    f16x2 w1 = {(_Float16)wv[2], (_Float16)wv[3]};
    f16x2 w2 = {(_Float16)wv[4], (_Float16)wv[5]};
    f16x2 w3 = {(_Float16)wv[6], (_Float16)wv[7]};
    const f16x2 zz = {(_Float16)0.f, (_Float16)0.f};
    float bl2v = bl2[0];
    const uint4* ap = (const uint4*)aH;
    int beg = noff[v], end = beg + ndeg[v];

#define EDGEP(U, P)                                                    \
    {                                                                  \
        f16x2 t;                                                       \
        t = u2h((U).x) + c0;                                           \
        t = __builtin_elementwise_max(t, zz);                          \
        P = __builtin_amdgcn_fdot2(t, w0, P, false);                   \
        t = u2h((U).y) + c1;                                           \
        t = __builtin_elementwise_max(t, zz);                          \
        P = __builtin_amdgcn_fdot2(t, w1, P, false);                   \
        t = u2h((U).z) + c2;                                           \
        t = __builtin_elementwise_max(t, zz);                          \
        P = __builtin_amdgcn_fdot2(t, w2, P, false);                   \
        t = u2h((U).w) + c3;                                           \
        t = __builtin_elementwise_max(t, zz);                          \
        P = __builtin_amdgcn_fdot2(t, w3, P, false);                   \
    }

    int k = beg + g;
    while (k + 8 < end) {
        int s0 = csr_src[k];
        int s1 = csr_src[k + 8];
        int e0 = csr_eid[k];
        int e1 = csr_eid[k + 8];
        uint4 u0 = ap[((u32)s0 << 3) + l];
        uint4 u1 = ap[((u32)s1 << 3) + l];
        float p0 = 0.f, p1 = 0.f;
        EDGEP(u0, p0);
        EDGEP(u1, p1);
        p0 += __shfl_xor(p0, 1, 64);
        p1 += __shfl_xor(p1, 1, 64);
        p0 += __shfl_xor(p0, 2, 64);
        p1 += __shfl_xor(p1, 2, 64);
        p0 += __shfl_xor(p0, 4, 64);
        p1 += __shfl_xor(p1, 4, 64);
        if (l == 0) {
            out[e0] = __builtin_amdgcn_rcpf(1.f + __expf(-(p0 + bl2v)));
            out[e1] = __builtin_amdgcn_rcpf(1.f + __expf(-(p1 + bl2v)));
        }
        k += 16;
    }
    if (k < end) {
        int s0 = csr_src[k];
        int e0 = csr_eid[k];
        uint4 u0 = ap[((u32)s0 << 3) + l];
        float p0 = 0.f;
        EDGEP(u0, p0);
        p0 += __shfl_xor(p0, 1, 64);
        p0 += __shfl_xor(p0, 2, 64);
        p0 += __shfl_xor(p0, 4, 64);
        if (l == 0) out[e0] = __builtin_amdgcn_rcpf(1.f + __expf(-(p0 + bl2v)));
    }
#undef EDGEP
}

extern "C" void kernel_launch(void* const* d_in, const int* in_sizes, int n_in,
                              void* d_out, int out_size, void* d_ws, size_t ws_size,
                              hipStream_t stream) {
    const float* x   = (const float*)d_in[0];
    const int*   ei  = (const int*)d_in[1];
    const float* W1  = (const float*)d_in[2];
    const float* b1  = (const float*)d_in[3];
    const float* W2  = (const float*)d_in[4];
    const float* b2  = (const float*)d_in[5];
    const float* Wl1 = (const float*)d_in[6];
    const float* bl1 = (const float*)d_in[7];
    const float* Wl2 = (const float*)d_in[8];
    const float* bl2 = (const float*)d_in[9];
    float* out = (float*)d_out;

    const int N = in_sizes[0] / IN_DIM;   // 100000
    const int E = in_sizes[1] / 2;        // 3200000
    const int* src = ei;
    const int* dst = ei + E;

    // workspace layout
    char* ws = (char*)d_ws;
    float* dinv    = (float*)ws;  ws += (size_t)(N + 64) * 4;
    int*   noff    = (int*)ws;    ws += (size_t)(N + 64) * 4;
    int*   ndeg    = (int*)ws;    ws += (size_t)(N + 64) * 4;
    int*   bcur    = (int*)ws;    ws += 1024;
    int*   csr_src = (int*)ws;    ws += (size_t)NB * CAP * 4;   // 14.3 MB
    int*   csr_eid = (int*)ws;    ws += (size_t)NB * CAP * 4;   // 14.3 MB
    u16*   tb      = (u16*)ws;    ws += (size_t)N * HID * 2;    // t1, t2 (bf16), a (fp16)
    float* h       = (float*)ws;  ws += (size_t)N * HID * 4;    // h, then z
    float* c       = (float*)ws;  ws += (size_t)N * HID * 4;
    u16*   cH      = (u16*)c;     // fp16 c(+bias) for decode (reuses c region)
    int2*  bpair   = (int2*)h;    // overlay: CSR-build staging (dead before gather1)

    const int TPB = 256;
    long nodeT = (long)N * HID;
    int nodeBlocks = (int)((nodeT + TPB - 1) / TPB);
    int tBlocks = (E + TILE - 1) / TILE;
    int gBlocks = (N + 63) / 64;
    size_t sortBytes = (size_t)(NKEY + 512 + 8) * sizeof(int);   // ~104.5 KB

    // ---- CSR build: padded fill -> (dl, window) counting sort ----
    binit<<<1, TPB, 0, stream>>>(bcur);
    bucket_fill<<<tBlocks, TPB, 0, stream>>>(src, dst, bcur, bpair, E);
    csr_scatter<<<NB, 512, sortBytes, stream>>>(bcur, bpair, csr_src, csr_eid,
                                                noff, ndeg, dinv);

    // ---- conv1: t1 = bf16((x@W1)*dinv) ; h = relu(gather + b1) ----
    mfma_gemm<IN_DIM, 64, 0><<<gBlocks, TPB, 0, stream>>>(x, W1, dinv, nullptr, tb, nullptr, N);
    gather_kernel<<<nodeBlocks, TPB, 0, stream>>>(noff, ndeg, csr_src, tb, dinv, b1, h, N, 1);

    // ---- conv2: t2 = bf16((h@W2)*dinv) ; z = gather + b2 (into h) ----
    mfma_gemm<HID, 64, 0><<<gBlocks, TPB, 0, stream>>>(h, W2, dinv, nullptr, tb, nullptr, N);
    gather_kernel<<<nodeBlocks, TPB, 0, stream>>>(noff, ndeg, csr_src, tb, dinv, b2, h, N, 0);

    // ---- decoder precompute: a = fp16(z@Wl1_top) into tb, cH = fp16(z@Wl1_bot + bl1) ----
    mfma_gemm<HID, 128, 2><<<gBlocks, TPB, 0, stream>>>(h, Wl1, nullptr, bl1, tb, cH, N);

    // ---- node-centric decode (fp16 packed) ----
    decode_kernel<<<nodeBlocks, TPB, 0, stream>>>(noff, ndeg, csr_src, csr_eid, tb, cH,
                                                  Wl2, bl2, out, N);
}